// Round 1
// 255.075 us; speedup vs baseline: 1.0820x; 1.0820x over previous
//
#include <hip/hip_runtime.h>
#include <hip/hip_bf16.h>
#include <cstdint>

#define BB 32
#define NN 2048
#define EE 4096
#define HH 4
#define CC 64
#define DD 256            // H*C == D_IN
#define MM (BB*NN)        // 65536 rows

typedef __attribute__((ext_vector_type(8))) short bf16x8;
typedef __attribute__((ext_vector_type(8))) unsigned short u16x8;
typedef __attribute__((ext_vector_type(4))) float f32x4;

__device__ __forceinline__ float b2f(__hip_bfloat16 x){ return __bfloat162float(x); }
__device__ __forceinline__ float u2f(unsigned short u){ return __uint_as_float((unsigned)u << 16); }
__device__ __forceinline__ unsigned short f2u(float f){
  __hip_bfloat16 h = __float2bfloat16(f);
  return *(unsigned short*)&h;
}
__device__ __forceinline__ float ldany(const void* p, int isf, size_t i){
  return isf ? ((const float*)p)[i] : b2f(((const __hip_bfloat16*)p)[i]);
}
__device__ __forceinline__ void gld_lds16(const void* g, void* l){
  __builtin_amdgcn_global_load_lds((const __attribute__((address_space(1))) uint32_t*)g,
                                   (__attribute__((address_space(3))) uint32_t*)l, 16, 0, 0);
}

// ---------------- dtype detection (unchanged — works) ----------------
__global__ void detect_kernel(const unsigned* __restrict__ w, int* __restrict__ flag){
  __shared__ int cnt;
  if(threadIdx.x == 0) cnt = 0;
  __syncthreads();
  int c = 0;
  #pragma unroll
  for(int i = 0; i < 4; ++i){
    unsigned v = w[threadIdx.x*4 + i];
    unsigned elo = (v >> 7) & 0xFFu;
    if(elo >= 100u && elo <= 150u) ++c;
  }
  atomicAdd(&cnt, c);
  __syncthreads();
  if(threadIdx.x == 0) *flag = (cnt < 128) ? 1 : 0;
}

// ---------------- param prep ----------------
// convX: XCD-affine — XCD k converts rows [8192k, 8192(k+1)) so the bf16 rows
// it writes stay in the L2 that the layer-1 GEMM on the same XCD will read.
__global__ __launch_bounds__(256) void convX_kernel(const void* __restrict__ src,
    unsigned short* __restrict__ dst, const int* __restrict__ flag){
  int isf = *flag;
  int blk  = blockIdx.x;                       // 16384 = 2048 * 8
  int vblk = (blk & 7)*2048 + (blk >> 3);      // XCD-affine remap
  size_t i = ((size_t)vblk*256 + threadIdx.x)*4;
  ushort4 o;
  if(isf){
    float4 v = *(const float4*)((const float*)src + i);
    o.x = f2u(v.x); o.y = f2u(v.y); o.z = f2u(v.z); o.w = f2u(v.w);
  } else {
    o = *(const ushort4*)((const unsigned short*)src + i);
  }
  *(ushort4*)(dst + i) = o;
}
__global__ __launch_bounds__(256) void convWT_kernel(const void* __restrict__ W,
    __hip_bfloat16* __restrict__ WT, const int* __restrict__ flag){
  int isf = *flag;
  int i = blockIdx.x*256 + threadIdx.x;       // 65536
  WT[i] = __float2bfloat16(ldany(W, isf, (size_t)(i & 255)*256 + (i >> 8)));
}
__global__ __launch_bounds__(256) void conv6_kernel(const void* s0, const void* s1,
    const void* s2, const void* s3, const void* s4, const void* s5,
    float* __restrict__ dst, const int* __restrict__ flag){
  int isf = *flag;
  int i = blockIdx.x*256 + threadIdx.x;       // [0, 1536)
  int seg = i >> 8, off = i & 255;
  const void* s = seg==0?s0 : seg==1?s1 : seg==2?s2 : seg==3?s3 : seg==4?s4 : s5;
  dst[i] = ldany(s, isf, off);
}

// ---------------- MFMA GEMM + fused attention-logit epilogue ----------------
// Grid: 1024 flat blocks. XCD-affine swizzle: XCD k owns row-blocks [64k,64k+64),
// and both col-blocks of a row-block are adjacent dispatches on the SAME XCD
// -> A-tile fetched once per pair from HBM, C rows written into the L2 that the
// gather on the same XCD will read.
__global__ __launch_bounds__(256) void mfma_gemm(const __hip_bfloat16* __restrict__ A,
    const __hip_bfloat16* __restrict__ BT, __hip_bfloat16* __restrict__ C,
    const float* __restrict__ attS, const float* __restrict__ attD,
    float* __restrict__ aS, float* __restrict__ aD)
{
  __shared__ __align__(16) short lds[128*128];     // staging (lA|lB) then C-tile
  short* lA = lds;
  short* lB = lds + 128*64;
  const int tid  = threadIdx.x;
  const int w    = tid >> 6, lane = tid & 63;
  const int dd   = blockIdx.x;                     // 0..1023
  const int xcd  = dd & 7, slot = dd >> 3;         // 128 slots per XCD
  const int rb   = xcd*64 + (slot >> 1), cb = slot & 1;
  const int row0 = rb*128, col0 = cb*128;
  const int wr   = (w & 1)*64, wc = (w >> 1)*64;
  const int lr   = lane >> 3;
  const int kb_g = (lane & 7) ^ lr;
  const int fm   = lane & 15, quad = lane >> 4;
  f32x4 acc[4][4] = {};

  for(int k0 = 0; k0 < 256; k0 += 64){
    #pragma unroll
    for(int c = 0; c < 4; ++c){
      int ra = w*32 + c*8;
      const short* ga = (const short*)A  + (size_t)(row0 + ra + lr)*DD + k0 + kb_g*8;
      const short* gb = (const short*)BT + (size_t)(col0 + ra + lr)*DD + k0 + kb_g*8;
      gld_lds16(ga, &lA[ra*64]);
      gld_lds16(gb, &lB[ra*64]);
    }
    __syncthreads();
    #pragma unroll
    for(int ks = 0; ks < 2; ++ks){
      bf16x8 af[4], bfr[4];
      int kb = ks*4 + quad;
      #pragma unroll
      for(int i = 0; i < 4; ++i){
        int m = wr + i*16 + fm;
        af[i]  = *(const bf16x8*)&lA[m*64 + ((kb ^ (m & 7))*8)];
        int n = wc + i*16 + fm;
        bfr[i] = *(const bf16x8*)&lB[n*64 + ((kb ^ (n & 7))*8)];
      }
      #pragma unroll
      for(int i = 0; i < 4; ++i)
        #pragma unroll
        for(int j = 0; j < 4; ++j)
          acc[i][j] = __builtin_amdgcn_mfma_f32_16x16x32_bf16(af[i], bfr[j], acc[i][j], 0, 0, 0);
    }
    __syncthreads();
  }

  // ---- fused attention logits (registers only; C/D layout col=fm, row=quad*4+r) ----
  const int headI = (col0 + wc) >> 6;          // this wave's head
  float ws_[4], wd_[4];
  #pragma unroll
  for(int j = 0; j < 4; ++j){
    ws_[j] = attS[headI*CC + j*16 + fm];
    wd_[j] = attD[headI*CC + j*16 + fm];
  }
  #pragma unroll
  for(int i = 0; i < 4; ++i){
    #pragma unroll
    for(int r = 0; r < 4; ++r){
      float s = 0.f, dv = 0.f;
      #pragma unroll
      for(int j = 0; j < 4; ++j){
        float v = acc[i][j][r];
        s  += v * ws_[j];
        dv += v * wd_[j];
      }
      // butterfly over the 16 fm-lanes (bits 0..3; quad bits untouched)
      #pragma unroll
      for(int m = 1; m <= 8; m <<= 1){
        s  += __shfl_xor(s,  m);
        dv += __shfl_xor(dv, m);
      }
      if(fm == i*4 + r){
        int row = row0 + wr + i*16 + quad*4 + r;
        aS[(size_t)row*HH + headI] = s;
        aD[(size_t)row*HH + headI] = dv;
      }
    }
  }

  // ---- C store via LDS transpose: conflict-free b16 writes (quad-XOR swizzle),
  //      16B-aligned b128 reads, 8 coalesced ushort8 global stores per thread ----
  #pragma unroll
  for(int i = 0; i < 4; ++i)
    #pragma unroll
    for(int j = 0; j < 4; ++j)
      #pragma unroll
      for(int r = 0; r < 4; ++r){
        int rl = wr + i*16 + quad*4 + r;
        int cl = wc + j*16 + fm;
        lds[rl*128 + (cl ^ ((rl & 12) << 2))] = (short)f2u(acc[i][j][r]);
      }
  __syncthreads();
  const int rr = tid >> 4, cc = (tid & 15)*8;
  #pragma unroll
  for(int p = 0; p < 8; ++p){
    int rl = p*16 + rr;
    u16x8 v = *(const u16x8*)&lds[rl*128 + (cc ^ ((rl & 12) << 2))];
    *(u16x8*)((unsigned short*)C + (size_t)(row0 + rl)*DD + col0 + cc) = v;
  }
}

// ---------------- CSR build ----------------
__global__ __launch_bounds__(256) void deg_kernel(const int* __restrict__ dst, int* __restrict__ degc)
{
  int idx = blockIdx.x*256 + threadIdx.x;
  if(idx >= BB*EE) return;
  int b = idx >> 12;
  atomicAdd(&degc[b*NN + dst[idx]], 1);
}

__global__ __launch_bounds__(256) void scan_kernel(int* __restrict__ degc, int* __restrict__ row_ptr)
{
  __shared__ int part[256];
  int b = blockIdx.x, t = threadIdx.x;
  int loc[8], s = 0;
  #pragma unroll
  for(int i = 0; i < 8; ++i){ loc[i] = s; s += degc[b*NN + t*8 + i]; }
  part[t] = s;
  __syncthreads();
  if(t == 0){
    int run = 0;
    for(int i = 0; i < 256; ++i){ int tmp = part[i]; part[i] = run; run += tmp; }
  }
  __syncthreads();
  int base = b*EE + part[t];
  #pragma unroll
  for(int i = 0; i < 8; ++i){
    int v = base + loc[i];
    row_ptr[b*(NN+1) + t*8 + i] = v;
    degc   [b*NN     + t*8 + i] = v;
  }
  if(t == 255) row_ptr[b*(NN+1) + NN] = base + s;
}

__global__ __launch_bounds__(256) void scatter_kernel(const int* __restrict__ src,
    const int* __restrict__ dst, int* __restrict__ cursor, unsigned short* __restrict__ srcList)
{
  int idx = blockIdx.x*256 + threadIdx.x;
  if(idx >= BB*EE) return;
  int b = idx >> 12;
  int pos = atomicAdd(&cursor[b*NN + dst[idx]], 1);
  srcList[pos] = (unsigned short)src[idx];
}

// ---------------- fused softmax + aggregate: one wave per (b, dst) ----------------
// Single pass: acc = exp(self)*h_self + sum exp(e)*h_src ; den accumulated alongside
// (bitwise-identical order to the previous alpha_kernel+gather split).
// XCD-affine: XCD k owns wid in [8192k, 8192(k+1)) = graphs 4k..4k+3, so all random
// per-graph H-row gathers hit the 4 MiB L2 that the GEMM on this XCD just wrote.
template<int LAYER>
__global__ __launch_bounds__(256) void gather_kernel(const __hip_bfloat16* __restrict__ H,
    const float* __restrict__ a_src, const float* __restrict__ a_dst,
    const int* __restrict__ row_ptr, const unsigned short* __restrict__ srcList,
    const float* __restrict__ bias, void* __restrict__ outp,
    const int* __restrict__ flag)
{
  int blk  = blockIdx.x;                         // 16384 = 2048 * 8
  int vblk = (blk & 7)*2048 + (blk >> 3);        // XCD-affine remap
  int wid  = vblk*4 + (int)(threadIdx.x >> 6);   // b*NN + d
  int lane = threadIdx.x & 63;
  int b = wid >> 11, d = wid & (NN-1);
  int head = lane >> 4;
  int start = row_ptr[b*(NN+1) + d];
  int end   = row_ptr[b*(NN+1) + d + 1];
  const unsigned short* Hu = (const unsigned short*)H;

  float adv = a_dst[wid*HH + head];
  float sv  = a_src[wid*HH + head] + adv;        // self-loop logit
  sv = sv > 0.f ? sv : 0.2f*sv;
  float exs = __expf(sv);

  ushort4 hv = *(const ushort4*)(Hu + (size_t)wid*DD + lane*4);
  f32x4 acc;
  acc.x = exs*u2f(hv.x); acc.y = exs*u2f(hv.y); acc.z = exs*u2f(hv.z); acc.w = exs*u2f(hv.w);
  float den = exs;

  // software-pipelined edge loop: prefetch next (s, a_src[s]) before using current H row
  int e = start;
  int s = 0; float ax = 0.f;
  if(e < end){ s = srcList[e]; ax = a_src[(b*NN + s)*HH + head]; }
  while(e < end){
    int sn = 0; float axn = 0.f;
    if(e + 1 < end){ sn = srcList[e+1]; axn = a_src[(b*NN + sn)*HH + head]; }
    float v = ax + adv;
    v = v > 0.f ? v : 0.2f*v;
    float ex = __expf(v);
    ushort4 hw = *(const ushort4*)(Hu + (size_t)(b*NN + s)*DD + lane*4);
    acc.x += ex*u2f(hw.x); acc.y += ex*u2f(hw.y); acc.z += ex*u2f(hw.z); acc.w += ex*u2f(hw.w);
    den += ex;
    s = sn; ax = axn; ++e;
  }
  float inv = 1.f / (den + 1e-16f);
  float4 bs = *(const float4*)(bias + lane*4);
  float o0 = acc.x*inv + bs.x, o1 = acc.y*inv + bs.y;
  float o2 = acc.z*inv + bs.z, o3 = acc.w*inv + bs.w;
  size_t oi = (size_t)wid*DD + lane*4;
  if(LAYER == 1){
    o0 = o0 > 0.f ? o0 : expm1f(o0);
    o1 = o1 > 0.f ? o1 : expm1f(o1);
    o2 = o2 > 0.f ? o2 : expm1f(o2);
    o3 = o3 > 0.f ? o3 : expm1f(o3);
    ushort4 ov = { f2u(o0), f2u(o1), f2u(o2), f2u(o3) };
    *(ushort4*)((unsigned short*)outp + oi) = ov;
  } else {
    if(*flag){
      float4 ov = { o0, o1, o2, o3 };
      *(float4*)((float*)outp + oi) = ov;
    } else {
      ushort4 ov = { f2u(o0), f2u(o1), f2u(o2), f2u(o3) };
      *(ushort4*)((unsigned short*)outp + oi) = ov;
    }
  }
}

extern "C" void kernel_launch(void* const* d_in, const int* in_sizes, int n_in,
                              void* d_out, int out_size, void* d_ws, size_t ws_size,
                              hipStream_t stream)
{
  const void* x_in = d_in[0];
  const int*  srcI = (const int*)d_in[1];
  const int*  dstI = (const int*)d_in[2];
  const void* W1   = d_in[3];
  const void* as1  = d_in[4];
  const void* ad1  = d_in[5];
  const void* b1   = d_in[6];
  const void* W2   = d_in[7];
  const void* as2  = d_in[8];
  const void* ad2  = d_in[9];
  const void* b2   = d_in[10];

  // Workspace (~67 MiB)
  char* ws = (char*)d_ws;
  __hip_bfloat16* R1  = (__hip_bfloat16*)ws; ws += (size_t)MM*DD*2;        // 32 MiB
  __hip_bfloat16* R2  = (__hip_bfloat16*)ws; ws += (size_t)MM*DD*2;        // 32 MiB
  float* a_src = (float*)ws; ws += (size_t)MM*HH*4;                        // 1 MiB
  float* a_dst = (float*)ws; ws += (size_t)MM*HH*4;                        // 1 MiB
  __hip_bfloat16* W1t = (__hip_bfloat16*)ws; ws += (size_t)DD*DD*2;        // 128 KiB
  __hip_bfloat16* W2t = (__hip_bfloat16*)ws; ws += (size_t)DD*DD*2;        // 128 KiB
  float* attf = (float*)ws; ws += 1536*4;
  int*   degc = (int*)ws;   ws += (size_t)BB*NN*4;
  int*   rowp = (int*)ws;   ws += (size_t)BB*(NN+1)*4;
  unsigned short* srcL = (unsigned short*)ws; ws += (size_t)BB*EE*2;
  int*   flag = (int*)ws;   ws += 8;

  const int gemmBlocks   = (MM/128)*(DD/128);      // 1024 flat (XCD-swizzled)
  const int edgeBlocks   = (BB*EE)/256;            // 512
  const int gatherBlocks = (MM*64)/256;            // 16384

  // ---- dtype detection + canonical params ----
  hipMemsetAsync(degc, 0, (size_t)BB*NN*4, stream);
  detect_kernel<<<1, 64, 0, stream>>>((const unsigned*)x_in, flag);
  convWT_kernel<<<DD*DD/256, 256, 0, stream>>>(W1, W1t, flag);
  convWT_kernel<<<DD*DD/256, 256, 0, stream>>>(W2, W2t, flag);
  conv6_kernel<<<6, 256, 0, stream>>>(as1, ad1, b1, as2, ad2, b2, attf, flag);
  convX_kernel<<<(int)(((size_t)MM*DD)/1024), 256, 0, stream>>>(x_in, (unsigned short*)R1, flag);

  // ---- CSR build ----
  deg_kernel    <<<edgeBlocks, 256, 0, stream>>>(dstI, degc);
  scan_kernel   <<<BB,         256, 0, stream>>>(degc, rowp);
  scatter_kernel<<<edgeBlocks, 256, 0, stream>>>(srcI, dstI, degc, srcL);

  // ---- layer 1 ----
  mfma_gemm<<<gemmBlocks, 256, 0, stream>>>(R1, W1t, R2, attf + 0, attf + 256, a_src, a_dst);
  gather_kernel<1><<<gatherBlocks, 256, 0, stream>>>(R2, a_src, a_dst, rowp, srcL,
                                                     attf + 512, R1, flag);  // R1 = x2
  // ---- layer 2 ----
  mfma_gemm<<<gemmBlocks, 256, 0, stream>>>(R1, W2t, R2, attf + 768, attf + 1024, a_src, a_dst);
  gather_kernel<2><<<gatherBlocks, 256, 0, stream>>>(R2, a_src, a_dst, rowp, srcL,
                                                     attf + 1280, d_out, flag);
}

// Round 2
// 242.614 us; speedup vs baseline: 1.1375x; 1.0514x over previous
//
#include <hip/hip_runtime.h>
#include <hip/hip_bf16.h>
#include <cstdint>

#define BB 32
#define NN 2048
#define EE 4096
#define HH 4
#define CC 64
#define DD 256            // H*C == D_IN
#define MM (BB*NN)        // 65536 rows

typedef __attribute__((ext_vector_type(8))) short bf16x8;
typedef __attribute__((ext_vector_type(8))) unsigned short u16x8;
typedef __attribute__((ext_vector_type(4))) float f32x4;

__device__ __forceinline__ float b2f(__hip_bfloat16 x){ return __bfloat162float(x); }
__device__ __forceinline__ float u2f(unsigned short u){ return __uint_as_float((unsigned)u << 16); }
__device__ __forceinline__ unsigned short f2u(float f){
  __hip_bfloat16 h = __float2bfloat16(f);
  return *(unsigned short*)&h;
}
__device__ __forceinline__ float ldany(const void* p, int isf, size_t i){
  return isf ? ((const float*)p)[i] : b2f(((const __hip_bfloat16*)p)[i]);
}
__device__ __forceinline__ void gld_lds16(const void* g, void* l){
  __builtin_amdgcn_global_load_lds((const __attribute__((address_space(1))) uint32_t*)g,
                                   (__attribute__((address_space(3))) uint32_t*)l, 16, 0, 0);
}

// ---------------- dtype detection (unchanged — works) ----------------
__global__ void detect_kernel(const unsigned* __restrict__ w, int* __restrict__ flag){
  __shared__ int cnt;
  if(threadIdx.x == 0) cnt = 0;
  __syncthreads();
  int c = 0;
  #pragma unroll
  for(int i = 0; i < 4; ++i){
    unsigned v = w[threadIdx.x*4 + i];
    unsigned elo = (v >> 7) & 0xFFu;
    if(elo >= 100u && elo <= 150u) ++c;
  }
  atomicAdd(&cnt, c);
  __syncthreads();
  if(threadIdx.x == 0) *flag = (cnt < 128) ? 1 : 0;
}

// ---------------- merged param prep: W1^T, W2^T, 6 att/bias vecs, degc zero ----------------
// blocks [0,256): W1t ; [256,512): W2t ; [512,518): att/bias ; [518,582): degc = 0
__global__ __launch_bounds__(256) void prep_kernel(const void* __restrict__ W1,
    const void* __restrict__ W2, __hip_bfloat16* __restrict__ W1t,
    __hip_bfloat16* __restrict__ W2t,
    const void* s0, const void* s1, const void* s2, const void* s3,
    const void* s4, const void* s5, float* __restrict__ attf,
    int* __restrict__ degc, const int* __restrict__ flag)
{
  int isf = *flag;
  int bid = blockIdx.x, t = threadIdx.x;
  if(bid < 512){
    const void* W = (bid < 256) ? W1 : W2;
    __hip_bfloat16* WT = (bid < 256) ? W1t : W2t;
    int i = (bid & 255)*256 + t;              // [0, 65536)
    WT[i] = __float2bfloat16(ldany(W, isf, (size_t)(i & 255)*256 + (i >> 8)));
  } else if(bid < 518){
    int i = (bid - 512)*256 + t;              // [0, 1536)
    int seg = i >> 8, off = i & 255;
    const void* s = seg==0?s0 : seg==1?s1 : seg==2?s2 : seg==3?s3 : seg==4?s4 : s5;
    attf[i] = ldany(s, isf, off);
  } else {
    int i = (bid - 518)*256 + t;              // [0, 16384) int4s = 65536 ints
    int4 z = {0,0,0,0};
    *((int4*)degc + i) = z;
  }
}

// ---------------- MFMA GEMM + fused attention-logit epilogue ----------------
// Grid: 1024 flat blocks. XCD-affine swizzle: XCD k owns row-blocks [64k,64k+64),
// and both col-blocks of a row-block are adjacent dispatches on the SAME XCD.
// DYNA=1: A may be fp32 (runtime flag) -> reg-stage + convert into swizzled LDS.
// DYNA=0: A is bf16 -> global_load_lds direct (no extra registers).
template<int DYNA>
__global__ __launch_bounds__(256) void mfma_gemm(const void* __restrict__ Ap,
    const __hip_bfloat16* __restrict__ BT, __hip_bfloat16* __restrict__ C,
    const float* __restrict__ attS, const float* __restrict__ attD,
    float* __restrict__ aS, float* __restrict__ aD, const int* __restrict__ flag)
{
  __shared__ __align__(16) short lds[128*128];     // staging (lA|lB) then C-tile
  short* lA = lds;
  short* lB = lds + 128*64;
  const int isf  = DYNA ? *flag : 0;
  const int tid  = threadIdx.x;
  const int w    = tid >> 6, lane = tid & 63;
  const int dd   = blockIdx.x;                     // 0..1023
  const int xcd  = dd & 7, slot = dd >> 3;         // 128 slots per XCD
  const int rb   = xcd*64 + (slot >> 1), cb = slot & 1;
  const int row0 = rb*128, col0 = cb*128;
  const int wr   = (w & 1)*64, wc = (w >> 1)*64;
  const int lr   = lane >> 3;
  const int kb_g = (lane & 7) ^ lr;
  const int fm   = lane & 15, quad = lane >> 4;
  f32x4 acc[4][4] = {};

  for(int k0 = 0; k0 < 256; k0 += 64){
    #pragma unroll
    for(int c = 0; c < 4; ++c){
      int ra = w*32 + c*8;
      const short* gb = (const short*)BT + (size_t)(col0 + ra + lr)*DD + k0 + kb_g*8;
      gld_lds16(gb, &lB[ra*64]);
    }
    if(DYNA && isf){
      // fp32 A: load 2x float4 per thread per chunk, convert, swizzled ds_write_b128
      const float* Af = (const float*)Ap;
      float4 ta[4], tb[4];
      #pragma unroll
      for(int i = 0; i < 4; ++i){
        int f8 = i*256 + tid;                  // [0,1024): (row m, k-block kb)
        int m = f8 >> 3, kb = f8 & 7;
        const float* p = Af + (size_t)(row0 + m)*DD + k0 + kb*8;
        ta[i] = *(const float4*)p;
        tb[i] = *(const float4*)(p + 4);
      }
      #pragma unroll
      for(int i = 0; i < 4; ++i){
        int f8 = i*256 + tid;
        int m = f8 >> 3, kb = f8 & 7;
        u16x8 o;
        o[0] = f2u(ta[i].x); o[1] = f2u(ta[i].y); o[2] = f2u(ta[i].z); o[3] = f2u(ta[i].w);
        o[4] = f2u(tb[i].x); o[5] = f2u(tb[i].y); o[6] = f2u(tb[i].z); o[7] = f2u(tb[i].w);
        *(u16x8*)&lA[m*64 + ((kb ^ (m & 7))*8)] = o;
      }
    } else {
      #pragma unroll
      for(int c = 0; c < 4; ++c){
        int ra = w*32 + c*8;
        const short* ga = (const short*)Ap + (size_t)(row0 + ra + lr)*DD + k0 + kb_g*8;
        gld_lds16(ga, &lA[ra*64]);
      }
    }
    __syncthreads();
    #pragma unroll
    for(int ks = 0; ks < 2; ++ks){
      bf16x8 af[4], bfr[4];
      int kb = ks*4 + quad;
      #pragma unroll
      for(int i = 0; i < 4; ++i){
        int m = wr + i*16 + fm;
        af[i]  = *(const bf16x8*)&lA[m*64 + ((kb ^ (m & 7))*8)];
        int n = wc + i*16 + fm;
        bfr[i] = *(const bf16x8*)&lB[n*64 + ((kb ^ (n & 7))*8)];
      }
      #pragma unroll
      for(int i = 0; i < 4; ++i)
        #pragma unroll
        for(int j = 0; j < 4; ++j)
          acc[i][j] = __builtin_amdgcn_mfma_f32_16x16x32_bf16(af[i], bfr[j], acc[i][j], 0, 0, 0);
    }
    __syncthreads();
  }

  // ---- fused attention logits (registers only; C/D layout col=fm, row=quad*4+r) ----
  const int headI = (col0 + wc) >> 6;          // this wave's head
  float ws_[4], wd_[4];
  #pragma unroll
  for(int j = 0; j < 4; ++j){
    ws_[j] = attS[headI*CC + j*16 + fm];
    wd_[j] = attD[headI*CC + j*16 + fm];
  }
  #pragma unroll
  for(int i = 0; i < 4; ++i){
    #pragma unroll
    for(int r = 0; r < 4; ++r){
      float s = 0.f, dv = 0.f;
      #pragma unroll
      for(int j = 0; j < 4; ++j){
        float v = acc[i][j][r];
        s  += v * ws_[j];
        dv += v * wd_[j];
      }
      // butterfly over the 16 fm-lanes (bits 0..3; quad bits untouched)
      #pragma unroll
      for(int m = 1; m <= 8; m <<= 1){
        s  += __shfl_xor(s,  m);
        dv += __shfl_xor(dv, m);
      }
      if(fm == i*4 + r){
        int row = row0 + wr + i*16 + quad*4 + r;
        aS[(size_t)row*HH + headI] = s;
        aD[(size_t)row*HH + headI] = dv;
      }
    }
  }

  // ---- C store via LDS transpose: conflict-free b16 writes (quad-XOR swizzle),
  //      16B-aligned b128 reads, 8 coalesced ushort8 global stores per thread ----
  #pragma unroll
  for(int i = 0; i < 4; ++i)
    #pragma unroll
    for(int j = 0; j < 4; ++j)
      #pragma unroll
      for(int r = 0; r < 4; ++r){
        int rl = wr + i*16 + quad*4 + r;
        int cl = wc + j*16 + fm;
        lds[rl*128 + (cl ^ ((rl & 12) << 2))] = (short)f2u(acc[i][j][r]);
      }
  __syncthreads();
  const int rr = tid >> 4, cc = (tid & 15)*8;
  #pragma unroll
  for(int p = 0; p < 8; ++p){
    int rl = p*16 + rr;
    u16x8 v = *(const u16x8*)&lds[rl*128 + (cc ^ ((rl & 12) << 2))];
    *(u16x8*)((unsigned short*)C + (size_t)(row0 + rl)*DD + col0 + cc) = v;
  }
}

// ---------------- CSR build ----------------
__global__ __launch_bounds__(256) void deg_kernel(const int* __restrict__ dst, int* __restrict__ degc)
{
  int idx = blockIdx.x*256 + threadIdx.x;
  if(idx >= BB*EE) return;
  int b = idx >> 12;
  atomicAdd(&degc[b*NN + dst[idx]], 1);
}

__global__ __launch_bounds__(256) void scan_kernel(int* __restrict__ degc, int* __restrict__ row_ptr)
{
  __shared__ int part[256];
  int b = blockIdx.x, t = threadIdx.x;
  int loc[8], s = 0;
  #pragma unroll
  for(int i = 0; i < 8; ++i){ loc[i] = s; s += degc[b*NN + t*8 + i]; }
  part[t] = s;
  __syncthreads();
  if(t == 0){
    int run = 0;
    for(int i = 0; i < 256; ++i){ int tmp = part[i]; part[i] = run; run += tmp; }
  }
  __syncthreads();
  int base = b*EE + part[t];
  #pragma unroll
  for(int i = 0; i < 8; ++i){
    int v = base + loc[i];
    row_ptr[b*(NN+1) + t*8 + i] = v;
    degc   [b*NN     + t*8 + i] = v;
  }
  if(t == 255) row_ptr[b*(NN+1) + NN] = base + s;
}

__global__ __launch_bounds__(256) void scatter_kernel(const int* __restrict__ src,
    const int* __restrict__ dst, int* __restrict__ cursor, unsigned short* __restrict__ srcList)
{
  int idx = blockIdx.x*256 + threadIdx.x;
  if(idx >= BB*EE) return;
  int b = idx >> 12;
  int pos = atomicAdd(&cursor[b*NN + dst[idx]], 1);
  srcList[pos] = (unsigned short)src[idx];
}

// ---------------- fused softmax + aggregate: one wave per (b, dst) ----------------
// Single pass: acc = exp(self)*h_self + sum exp(e)*h_src ; den accumulated alongside.
// XCD-affine: XCD k owns wid in [8192k, 8192(k+1)) = graphs 4k..4k+3, so all random
// per-graph H-row gathers hit the 4 MiB L2 that the GEMM on this XCD just wrote.
template<int LAYER>
__global__ __launch_bounds__(256) void gather_kernel(const __hip_bfloat16* __restrict__ H,
    const float* __restrict__ a_src, const float* __restrict__ a_dst,
    const int* __restrict__ row_ptr, const unsigned short* __restrict__ srcList,
    const float* __restrict__ bias, void* __restrict__ outp,
    const int* __restrict__ flag)
{
  int blk  = blockIdx.x;                         // 16384 = 2048 * 8
  int vblk = (blk & 7)*2048 + (blk >> 3);        // XCD-affine remap
  int wid  = vblk*4 + (int)(threadIdx.x >> 6);   // b*NN + d
  int lane = threadIdx.x & 63;
  int b = wid >> 11, d = wid & (NN-1);
  int head = lane >> 4;
  int start = row_ptr[b*(NN+1) + d];
  int end   = row_ptr[b*(NN+1) + d + 1];
  const unsigned short* Hu = (const unsigned short*)H;

  float adv = a_dst[wid*HH + head];
  float sv  = a_src[wid*HH + head] + adv;        // self-loop logit
  sv = sv > 0.f ? sv : 0.2f*sv;
  float exs = __expf(sv);

  ushort4 hv = *(const ushort4*)(Hu + (size_t)wid*DD + lane*4);
  f32x4 acc;
  acc.x = exs*u2f(hv.x); acc.y = exs*u2f(hv.y); acc.z = exs*u2f(hv.z); acc.w = exs*u2f(hv.w);
  float den = exs;

  // software-pipelined edge loop: prefetch next (s, a_src[s]) before using current H row
  int e = start;
  int s = 0; float ax = 0.f;
  if(e < end){ s = srcList[e]; ax = a_src[(b*NN + s)*HH + head]; }
  while(e < end){
    int sn = 0; float axn = 0.f;
    if(e + 1 < end){ sn = srcList[e+1]; axn = a_src[(b*NN + sn)*HH + head]; }
    float v = ax + adv;
    v = v > 0.f ? v : 0.2f*v;
    float ex = __expf(v);
    ushort4 hw = *(const ushort4*)(Hu + (size_t)(b*NN + s)*DD + lane*4);
    acc.x += ex*u2f(hw.x); acc.y += ex*u2f(hw.y); acc.z += ex*u2f(hw.z); acc.w += ex*u2f(hw.w);
    den += ex;
    s = sn; ax = axn; ++e;
  }
  float inv = 1.f / (den + 1e-16f);
  float4 bs = *(const float4*)(bias + lane*4);
  float o0 = acc.x*inv + bs.x, o1 = acc.y*inv + bs.y;
  float o2 = acc.z*inv + bs.z, o3 = acc.w*inv + bs.w;
  size_t oi = (size_t)wid*DD + lane*4;
  if(LAYER == 1){
    o0 = o0 > 0.f ? o0 : expm1f(o0);
    o1 = o1 > 0.f ? o1 : expm1f(o1);
    o2 = o2 > 0.f ? o2 : expm1f(o2);
    o3 = o3 > 0.f ? o3 : expm1f(o3);
    ushort4 ov = { f2u(o0), f2u(o1), f2u(o2), f2u(o3) };
    *(ushort4*)((unsigned short*)outp + oi) = ov;
  } else {
    if(*flag){
      float4 ov = { o0, o1, o2, o3 };
      *(float4*)((float*)outp + oi) = ov;
    } else {
      ushort4 ov = { f2u(o0), f2u(o1), f2u(o2), f2u(o3) };
      *(ushort4*)((unsigned short*)outp + oi) = ov;
    }
  }
}

extern "C" void kernel_launch(void* const* d_in, const int* in_sizes, int n_in,
                              void* d_out, int out_size, void* d_ws, size_t ws_size,
                              hipStream_t stream)
{
  const void* x_in = d_in[0];
  const int*  srcI = (const int*)d_in[1];
  const int*  dstI = (const int*)d_in[2];
  const void* W1   = d_in[3];
  const void* as1  = d_in[4];
  const void* ad1  = d_in[5];
  const void* b1   = d_in[6];
  const void* W2   = d_in[7];
  const void* as2  = d_in[8];
  const void* ad2  = d_in[9];
  const void* b2   = d_in[10];

  // Workspace (~67 MiB)
  char* ws = (char*)d_ws;
  __hip_bfloat16* R1  = (__hip_bfloat16*)ws; ws += (size_t)MM*DD*2;        // 32 MiB
  __hip_bfloat16* R2  = (__hip_bfloat16*)ws; ws += (size_t)MM*DD*2;        // 32 MiB
  float* a_src = (float*)ws; ws += (size_t)MM*HH*4;                        // 1 MiB
  float* a_dst = (float*)ws; ws += (size_t)MM*HH*4;                        // 1 MiB
  __hip_bfloat16* W1t = (__hip_bfloat16*)ws; ws += (size_t)DD*DD*2;        // 128 KiB
  __hip_bfloat16* W2t = (__hip_bfloat16*)ws; ws += (size_t)DD*DD*2;        // 128 KiB
  float* attf = (float*)ws; ws += 1536*4;
  int*   degc = (int*)ws;   ws += (size_t)BB*NN*4;
  int*   rowp = (int*)ws;   ws += (size_t)BB*(NN+1)*4;
  unsigned short* srcL = (unsigned short*)ws; ws += (size_t)BB*EE*2;
  int*   flag = (int*)ws;   ws += 8;

  const int gemmBlocks   = (MM/128)*(DD/128);      // 1024 flat (XCD-swizzled)
  const int edgeBlocks   = (BB*EE)/256;            // 512
  const int gatherBlocks = (MM*64)/256;            // 16384

  // ---- dtype detection + canonical params (+ degc zeroing, all in one prep) ----
  detect_kernel<<<1, 64, 0, stream>>>((const unsigned*)x_in, flag);
  prep_kernel<<<582, 256, 0, stream>>>(W1, W2, W1t, W2t,
                                       as1, ad1, b1, as2, ad2, b2, attf, degc, flag);

  // ---- CSR build ----
  deg_kernel    <<<edgeBlocks, 256, 0, stream>>>(dstI, degc);
  scan_kernel   <<<BB,         256, 0, stream>>>(degc, rowp);
  scatter_kernel<<<edgeBlocks, 256, 0, stream>>>(srcI, dstI, degc, srcL);

  // ---- layer 1 (A = x_in, fp32 or bf16 — converted in-kernel) ----
  mfma_gemm<1><<<gemmBlocks, 256, 0, stream>>>(x_in, W1t, R2, attf + 0, attf + 256,
                                               a_src, a_dst, flag);
  gather_kernel<1><<<gatherBlocks, 256, 0, stream>>>(R2, a_src, a_dst, rowp, srcL,
                                                     attf + 512, R1, flag);  // R1 = x2
  // ---- layer 2 (A = R1, always bf16) ----
  mfma_gemm<0><<<gemmBlocks, 256, 0, stream>>>(R1, W2t, R2, attf + 768, attf + 1024,
                                               a_src, a_dst, flag);
  gather_kernel<2><<<gatherBlocks, 256, 0, stream>>>(R2, a_src, a_dst, rowp, srcL,
                                                     attf + 1280, d_out, flag);
}